// Round 12
// baseline (130.155 us; speedup 1.0000x reference)
//
#include <hip/hip_runtime.h>
#include <hip/hip_bf16.h>
#include <stdint.h>

// ---------------- problem constants (fixed instance) ----------------
#define M_DIM 8192   // B*S
#define K_DIM 2048   // D_IN
#define N_DIM 2048   // D_OUT
#define RANK  64
#define ALPHA_F 1.0f

typedef __attribute__((ext_vector_type(4))) float  f32x4;
typedef __attribute__((ext_vector_type(8))) short  s16x8;

// round-to-nearest-even f32 -> bf16 (finite inputs)
__device__ __forceinline__ unsigned short f2bf(float f) {
    unsigned int u = __float_as_uint(f);
    u += 0x7fffu + ((u >> 16) & 1u);
    return (unsigned short)(u >> 16);
}

__device__ __forceinline__ void gload_lds16(const void* g, void* l) {
    __builtin_amdgcn_global_load_lds(
        (const __attribute__((address_space(1))) void*)g,
        (__attribute__((address_space(3))) void*)l, 16, 0, 0);
}

// ---------------- prep kernels ----------------

// T2[r][i] = (sigma @ R @ Vt)[r][i]; grid 512 blocks: r = bid>>3, 256 cols per block.
__global__ __launch_bounds__(256) void t2sr_kernel(const float* __restrict__ sigma,
                                                   const float* __restrict__ Rm,
                                                   const float* __restrict__ Vt,
                                                   float* __restrict__ T2) {
    __shared__ float sSig[64];
    __shared__ float sRow[64];
    const int r = blockIdx.x >> 3;
    const int i = (blockIdx.x & 7) * 256 + threadIdx.x;
    if (threadIdx.x < 64) sSig[threadIdx.x] = sigma[r * 64 + threadIdx.x];
    __syncthreads();
    if (threadIdx.x < 64) {
        float a = 0.f;
        #pragma unroll 8
        for (int k = 0; k < 64; ++k) a += sSig[k] * Rm[k * 64 + threadIdx.x];
        sRow[threadIdx.x] = a;
    }
    __syncthreads();
    float a = 0.f;
    #pragma unroll 8
    for (int k = 0; k < 64; ++k) a += sRow[k] * Vt[k * 2048 + i];
    T2[r * 2048 + i] = a;
}

// Weff bf16 tiles only (x-cast now fused into the GEMM's A-staging).
__global__ __launch_bounds__(256) void weff_kernel(const float* __restrict__ W,
                                                   const float* __restrict__ U,
                                                   const float* __restrict__ T2,
                                                   unsigned short* __restrict__ Wb) {
    __shared__ float sU[64 * 65];
    __shared__ float sT[64 * 64];
    int to = blockIdx.x >> 5;
    int ti = blockIdx.x & 31;
    int o0 = to * 64, i0 = ti * 64;
    for (int e = 0; e < 16; ++e) {
        int li = threadIdx.x + e * 256;
        int hi = li >> 6, lo = li & 63;
        sU[hi * 65 + lo] = U[(size_t)o0 * 64 + li];
        sT[li]           = T2[hi * 2048 + i0 + lo];
    }
    __syncthreads();
    int o  = threadIdx.x >> 2;
    int ib = (threadIdx.x & 3) * 16;
    float acc[16] = {};
    for (int k = 0; k < 64; ++k) {
        float u = sU[o * 65 + k];
        #pragma unroll
        for (int j = 0; j < 16; ++j) acc[j] += u * sT[k * 64 + ib + j];
    }
    size_t base = (size_t)(o0 + o) * 2048 + i0 + ib;
    #pragma unroll
    for (int j = 0; j < 16; ++j)
        Wb[base + j] = f2bf(W[base + j] + ALPHA_F * acc[j]);
}

// ---------------- 256x256 8-phase bf16 MFMA GEMM, fused fp32-A cast ----------------
// C[m][n] = sum_k x[m][k]*B[n][k] + bias[n];  x fp32 (cast in-register), B bf16.
// A-staging: {global f32x4 loads (early) -> cvt bf16 -> ds_write_b128 to the same
// slot-swizzled LDS bytes gload_lds used}. Each A-write phase ends with lgkmcnt(0)
// AFTER its MFMA (writes drain free there; reads already consumed) so ds_writes are
// published at the wave's next barrier. B-staging keeps gload_lds. The in-order vmcnt
// queue means each cvt's compiler-inserted wait also drains the wave's older B-stage
// loads -> tile t+2 stages provably drained before barrier8; VMWAIT8 keeps the newest
// 4 A-loads + 4 B-stage loads in flight (counted, never 0 mid-loop).

#define AHALF_E (128 * K_DIM)   // elements per 128-row half panel

__device__ __forceinline__ void stage_slot(const unsigned short* g0, const unsigned short* g1,
                                           char* smp, int ldsbase, int wave) {
    gload_lds16(g0, smp + ldsbase + wave * 1024);
    gload_lds16(g1, smp + ldsbase + 8192 + wave * 1024);
}

__device__ __forceinline__ void loadA16(const float* g0, const float* g1, f32x4 (&r)[4]) {
    r[0] = *(const f32x4*)(g0);
    r[1] = *(const f32x4*)(g0 + 4);
    r[2] = *(const f32x4*)(g1);
    r[3] = *(const f32x4*)(g1 + 4);
}

__device__ __forceinline__ s16x8 cvt8(f32x4 a, f32x4 b) {
    s16x8 o;
    o[0] = (short)f2bf(a[0]); o[1] = (short)f2bf(a[1]);
    o[2] = (short)f2bf(a[2]); o[3] = (short)f2bf(a[3]);
    o[4] = (short)f2bf(b[0]); o[5] = (short)f2bf(b[1]);
    o[6] = (short)f2bf(b[2]); o[7] = (short)f2bf(b[3]);
    return o;
}

__device__ __forceinline__ void writeA16(char* sm, int ldsbase, int tid, f32x4 (&r)[4]) {
    *(s16x8*)(sm + ldsbase + tid * 16)        = cvt8(r[0], r[1]);
    *(s16x8*)(sm + ldsbase + 8192 + tid * 16) = cvt8(r[2], r[3]);
}

// fragment reads, first-MFMA operands first (R10 ordering)
template <int B_, int P_>
__device__ __forceinline__ void read_frags(const char* sm, s16x8 (&af)[4],
                                           s16x8 (&bfr4)[4][2],
                                           int wr8, int wc4, int laneoff) {
    constexpr int ks = P_ & 1, mh = P_ >> 1;
    af[0] = *(const s16x8*)(sm + B_ * 32768 + ((wr8 + mh * 4 + 0) * 2 + ks) * 1024 + laneoff);
    if (P_ < 2) {
        #pragma unroll
        for (int ni = 0; ni < 4; ++ni)
            bfr4[ni][ks] = *(const s16x8*)(sm + 65536 + B_ * 32768 +
                              ((wc4 + ni) * 2 + ks) * 1024 + laneoff);
    }
    #pragma unroll
    for (int mi = 1; mi < 4; ++mi)
        af[mi] = *(const s16x8*)(sm + B_ * 32768 +
                    ((wr8 + mh * 4 + mi) * 2 + ks) * 1024 + laneoff);
}

template <int P_>
__device__ __forceinline__ void mfma_p(f32x4 (&acc)[8][4], s16x8 (&af)[4], s16x8 (&bfr4)[4][2]) {
    constexpr int ks = P_ & 1, mh = P_ >> 1;
    #pragma unroll
    for (int mi = 0; mi < 4; ++mi)
        #pragma unroll
        for (int ni = 0; ni < 4; ++ni)
            acc[mh * 4 + mi][ni] = __builtin_amdgcn_mfma_f32_16x16x32_bf16(
                af[mi], bfr4[ni][ks], acc[mh * 4 + mi][ni], 0, 0, 0);
}

#define VMWAIT2 do { asm volatile("s_waitcnt vmcnt(2)" ::: "memory"); \
                     __builtin_amdgcn_sched_barrier(0); } while (0)
#define VMWAIT4 do { asm volatile("s_waitcnt vmcnt(4)" ::: "memory"); \
                     __builtin_amdgcn_sched_barrier(0); } while (0)
#define VMWAIT8 do { asm volatile("s_waitcnt vmcnt(8)" ::: "memory"); \
                     __builtin_amdgcn_sched_barrier(0); } while (0)
#define LGKM0   do { asm volatile("s_waitcnt lgkmcnt(0)" ::: "memory"); } while (0)

// single-barrier phase; PRE runs pre-barrier, POST after the MFMA cluster
#define DO_PHASE(B_, P_, PRE_STMT, WAIT_STMT, POST_STMT)                \
  { s16x8 af[4];                                                        \
    read_frags<B_, P_>(sm, af, bfr4, wr8, wc4, laneoff);                \
    PRE_STMT;                                                           \
    WAIT_STMT;                                                          \
    __builtin_amdgcn_s_barrier();                                       \
    __builtin_amdgcn_s_setprio(1);                                      \
    mfma_p<P_>(acc, af, bfr4);                                          \
    __builtin_amdgcn_s_setprio(0);                                      \
    POST_STMT; }

#define STAGE_B(half, buf, kel) \
    stage_slot(Bg + (half) * AHALF_E + (kel) + soff0, Bg + (half) * AHALF_E + (kel) + soff1, \
               sm, 65536 + (buf) * 32768 + (half) * 16384, wave)
#define LOAD_A(half, kel, R) \
    loadA16(Axf + (half) * AHALF_E + (kel) + soff0, Axf + (half) * AHALF_E + (kel) + soff1, R)
#define WRITE_A(half, buf, R) writeA16(sm, (buf) * 32768 + (half) * 16384, tid, R)

__global__ __launch_bounds__(512, 2)
void gemm8_kernel(const float* __restrict__ X,
                  const unsigned short* __restrict__ Bm,
                  const float* __restrict__ bias,
                  float* __restrict__ C) {
    extern __shared__ char sm[];

    const int tid  = threadIdx.x;
    const int wave = tid >> 6;
    const int lane = tid & 63;
    const int wr8  = (wave >> 2) * 8;   // A subtile row base (16-row units)
    const int wc4  = (wave & 3) * 4;    // B subtile row base

    // XCD-bijective swizzle: 256 blocks, 256 % 8 == 0
    const int bid = blockIdx.x;
    const int swz = (bid & 7) * 32 + (bid >> 3);
    const int rowM0 = (swz >> 3) * 256;   // 32 M-tiles
    const int rowN0 = (swz & 7) * 256;    // 8 N-tiles

    const float*          Axf = X  + (size_t)rowM0 * K_DIM;
    const unsigned short* Bg  = Bm + (size_t)rowN0 * K_DIM;

    // staging source: linear LDS dest byte D -> global element (slot-swizzled layout)
    int soff0, soff1;
    {
        #pragma unroll
        for (int ld = 0; ld < 2; ++ld) {
            int D   = ld * 8192 + tid * 16;
            int st  = D >> 10;           // subtile unit in half-panel
            int s   = (D >> 4) & 63;     // slot within subtile
            int row = s >> 2;
            int kq  = (s & 3) ^ ((s >> 3) & 3);
            int e = ((st >> 1) * 16 + row) * K_DIM + (st & 1) * 32 + kq * 8;
            if (ld == 0) soff0 = e; else soff1 = e;
        }
    }

    // fragment ds_read lane offset (slot-swizzled)
    const int laneoff = ((lane & 15) * 4 + ((lane >> 4) ^ (((lane & 15) >> 1) & 3))) * 16;

    f32x4 acc[8][4] = {};
    s16x8 bfr4[4][2];
    f32x4 rA0[4], rA1[4];

    // ---- prologue: tile0 A via load+cvt+write, B tile0->buf0, tile1 B->buf1 ----
    LOAD_A(0, 0, rA0);
    LOAD_A(1, 0, rA1);
    WRITE_A(0, 0, rA0);     // compiler vmcnt-waits drain the A loads
    WRITE_A(1, 0, rA1);
    STAGE_B(0, 0, 0);
    STAGE_B(1, 0, 0);
    STAGE_B(0, 1, 64);
    STAGE_B(1, 1, 64);
    VMWAIT4;                 // keep tile1 B (4 newest) in flight; tile0 B drained
    LGKM0;                   // tile0 A ds_writes published
    LOAD_A(0, 64, rA0);      // tile1 h0 for ph1's write
    __builtin_amdgcn_s_barrier();

    // ---- main loop: 16 iterations x 2 K-tiles ----
    // Ring (tile t=2i in buf0, t+1 in buf1):
    //  ph1: write A-buf1 h0 (rA0), load rA1=A(h1,t+1)   ph2: write A-buf1 h1 (rA1)
    //  ph3: -                                           ph4: B-buf0(t+2) h0 [vmcnt(2)]
    //  ph5: B-buf0 h1, load rA0=A(h0,t+2)               ph6: write A-buf0 h0, load rA1=A(h1,t+2)
    //  ph7: write A-buf0 h1; POST: lgkm0 + load rA0(t+3) ph8: B-buf1(t+3) h0+h1 [vmcnt(8)]
    for (int i = 0; i < 16; ++i) {
        const int kA12 = (2 * i + 1) * 64;          // tile 2i+1 (always valid)
        const int kN2  = ((2 * i + 2) & 31) * 64;   // tile 2i+2 (clamped tail)
        const int kN3  = ((2 * i + 3) & 31) * 64;   // tile 2i+3 (clamped tail)

        DO_PHASE(0, 0, (WRITE_A(0, 1, rA0), LOAD_A(1, kA12, rA1)), ((void)0), LGKM0);
        DO_PHASE(0, 1, (WRITE_A(1, 1, rA1)),                        ((void)0), LGKM0);
        DO_PHASE(0, 2, ((void)0),                                   ((void)0), ((void)0));
        DO_PHASE(0, 3, (STAGE_B(0, 0, kN2)),                        VMWAIT2,   ((void)0));
        DO_PHASE(1, 0, (STAGE_B(1, 0, kN2), LOAD_A(0, kN2, rA0)),   ((void)0), ((void)0));
        DO_PHASE(1, 1, (WRITE_A(0, 0, rA0), LOAD_A(1, kN2, rA1)),   ((void)0), LGKM0);
        DO_PHASE(1, 2, (WRITE_A(1, 0, rA1)),                        ((void)0),
                 do { LGKM0; LOAD_A(0, kN3, rA0); } while (0));
        DO_PHASE(1, 3, (STAGE_B(0, 1, kN3), STAGE_B(1, 1, kN3)),    VMWAIT8,   ((void)0));
    }

    // ---- epilogue: D row=(lane>>4)*4+r, col=lane&15 per 16x16 fragment ----
    const int col0  = rowN0 + (wc4 >> 2) * 64 + (lane & 15);
    const int row0w = rowM0 + (wr8 >> 3) * 128 + (lane >> 4) * 4;
    float bv[4];
    #pragma unroll
    for (int ni = 0; ni < 4; ++ni) bv[ni] = bias[col0 + ni * 16];
    #pragma unroll
    for (int mi = 0; mi < 8; ++mi)
        #pragma unroll
        for (int ni = 0; ni < 4; ++ni)
            #pragma unroll
            for (int r = 0; r < 4; ++r)
                C[(size_t)(row0w + mi * 16 + r) * N_DIM + col0 + ni * 16] =
                    acc[mi][ni][r] + bv[ni];
}

// ---------------- fp32 fallback (only if ws too small for bf16 path) ----------------

__global__ __launch_bounds__(256) void xt_kernel(const float* __restrict__ x,
                                                 const float* __restrict__ T2,
                                                 float* __restrict__ xt) {
    int idx = blockIdx.x * 256 + threadIdx.x;
    int m = idx >> 6, r = idx & 63;
    float acc = 0.f;
    for (int i = 0; i < K_DIM; ++i) acc += x[(size_t)m * K_DIM + i] * T2[r * K_DIM + i];
    xt[idx] = acc;
}

__global__ __launch_bounds__(256) void fgemm_kernel(const float* __restrict__ A,
                                                    const float* __restrict__ W,
                                                    const float* __restrict__ xt,
                                                    const float* __restrict__ U,
                                                    const float* __restrict__ bias,
                                                    float* __restrict__ C) {
    __shared__ float sA[64][17];
    __shared__ float sW[64][17];
    int bm = blockIdx.x >> 5;
    int bn = blockIdx.x & 31;
    int m0 = bm * 64, n0 = bn * 64;
    int tid = threadIdx.x;
    int tm = tid >> 4, tn = tid & 15;
    float acc[4][4] = {};
    for (int k0 = 0; k0 < K_DIM; k0 += 16) {
        int lr = tid >> 2;
        int lc = (tid & 3) * 4;
        #pragma unroll
        for (int j = 0; j < 4; ++j) {
            sA[lr][lc + j] = A[(size_t)(m0 + lr) * K_DIM + k0 + lc + j];
            sW[lr][lc + j] = W[(size_t)(n0 + lr) * K_DIM + k0 + lc + j];
        }
        __syncthreads();
        #pragma unroll
        for (int kk = 0; kk < 16; ++kk) {
            float av[4], wv[4];
            #pragma unroll
            for (int i = 0; i < 4; ++i) av[i] = sA[tm * 4 + i][kk];
            #pragma unroll
            for (int j = 0; j < 4; ++j) wv[j] = sW[tn * 4 + j][kk];
            #pragma unroll
            for (int i = 0; i < 4; ++i)
                #pragma unroll
                for (int j = 0; j < 4; ++j) acc[i][j] += av[i] * wv[j];
        }
        __syncthreads();
    }
    #pragma unroll
    for (int i = 0; i < 4; ++i) {
        int m = m0 + tm * 4 + i;
        #pragma unroll
        for (int j = 0; j < 4; ++j) {
            int n = n0 + tn * 4 + j;
            float l = 0.f;
            for (int r = 0; r < RANK; ++r) l += xt[(size_t)m * RANK + r] * U[(size_t)n * RANK + r];
            C[(size_t)m * N_DIM + n] = acc[i][j] + l + bias[n];
        }
    }
}

// ---------------- launch ----------------
extern "C" void kernel_launch(void* const* d_in, const int* in_sizes, int n_in,
                              void* d_out, int out_size, void* d_ws, size_t ws_size,
                              hipStream_t stream) {
    const float* x      = (const float*)d_in[0];
    const float* weight = (const float*)d_in[1];
    const float* bias   = (const float*)d_in[2];
    const float* U      = (const float*)d_in[3];
    const float* sigma  = (const float*)d_in[4];
    const float* Rm     = (const float*)d_in[5];
    const float* Vt     = (const float*)d_in[6];
    float* out = (float*)d_out;
    char* ws = (char*)d_ws;

    const size_t WB_BYTES = (size_t)N_DIM * K_DIM * 2;   // 8 MB
    const size_t T2_BYTES = (size_t)RANK * K_DIM * 4;    // 512 KB
    const size_t MAIN_NEED = WB_BYTES + T2_BYTES;

    if (ws_size >= MAIN_NEED) {
        unsigned short* wb = (unsigned short*)ws;
        float* T2 = (float*)(ws + WB_BYTES);

        hipFuncSetAttribute((const void*)gemm8_kernel,
                            hipFuncAttributeMaxDynamicSharedMemorySize, 131072);

        t2sr_kernel<<<512, 256, 0, stream>>>(sigma, Rm, Vt, T2);
        weff_kernel<<<(N_DIM / 64) * (K_DIM / 64), 256, 0, stream>>>(weight, U, T2, wb);
        gemm8_kernel<<<(M_DIM / 256) * (N_DIM / 256), 512, 131072, stream>>>(x, wb, bias, out);
    } else {
        float* T2 = (float*)ws;
        float* xt = (float*)(ws + T2_BYTES);
        t2sr_kernel<<<512, 256, 0, stream>>>(sigma, Rm, Vt, T2);
        xt_kernel<<<(M_DIM * RANK) / 256, 256, 0, stream>>>(x, T2, xt);
        fgemm_kernel<<<(M_DIM / 64) * (N_DIM / 64), 256, 0, stream>>>(x, weight, xt, U, bias, out);
    }
}

// Round 13
// 93.519 us; speedup vs baseline: 1.3917x; 1.3917x over previous
//
#include <hip/hip_runtime.h>
#include <hip/hip_bf16.h>
#include <stdint.h>

// ---------------- problem constants (fixed instance) ----------------
#define M_DIM 8192   // B*S
#define K_DIM 2048   // D_IN
#define N_DIM 2048   // D_OUT
#define RANK  64
#define ALPHA_F 1.0f

typedef __attribute__((ext_vector_type(4))) float  f32x4;
typedef __attribute__((ext_vector_type(8))) short  s16x8;

// round-to-nearest-even f32 -> bf16 (finite inputs)
__device__ __forceinline__ unsigned short f2bf(float f) {
    unsigned int u = __float_as_uint(f);
    u += 0x7fffu + ((u >> 16) & 1u);
    return (unsigned short)(u >> 16);
}

__device__ __forceinline__ void gload_lds16(const void* g, void* l) {
    __builtin_amdgcn_global_load_lds(
        (const __attribute__((address_space(1))) void*)g,
        (__attribute__((address_space(3))) void*)l, 16, 0, 0);
}

// ---------------- prep kernels ----------------

// T2[r][i] = (sigma @ R @ Vt)[r][i]; grid 512 blocks: r = bid>>3, 256 cols per block.
__global__ __launch_bounds__(256) void t2sr_kernel(const float* __restrict__ sigma,
                                                   const float* __restrict__ Rm,
                                                   const float* __restrict__ Vt,
                                                   float* __restrict__ T2) {
    __shared__ float sSig[64];
    __shared__ float sRow[64];
    const int r = blockIdx.x >> 3;
    const int i = (blockIdx.x & 7) * 256 + threadIdx.x;
    if (threadIdx.x < 64) sSig[threadIdx.x] = sigma[r * 64 + threadIdx.x];
    __syncthreads();
    if (threadIdx.x < 64) {
        float a = 0.f;
        #pragma unroll 8
        for (int k = 0; k < 64; ++k) a += sSig[k] * Rm[k * 64 + threadIdx.x];
        sRow[threadIdx.x] = a;
    }
    __syncthreads();
    float a = 0.f;
    #pragma unroll 8
    for (int k = 0; k < 64; ++k) a += sRow[k] * Vt[k * 2048 + i];
    T2[r * 2048 + i] = a;
}

// Fused: blocks [0,1024) compute Weff bf16 tiles; blocks [1024,3072) cast x -> bf16.
__global__ __launch_bounds__(256) void weffcast_kernel(const float* __restrict__ W,
                                                       const float* __restrict__ U,
                                                       const float* __restrict__ T2,
                                                       unsigned short* __restrict__ Wb,
                                                       const float* __restrict__ x,
                                                       unsigned short* __restrict__ xb) {
    __shared__ float sU[64 * 65];
    __shared__ float sT[64 * 64];
    if (blockIdx.x < 1024) {
        int to = blockIdx.x >> 5;
        int ti = blockIdx.x & 31;
        int o0 = to * 64, i0 = ti * 64;
        for (int e = 0; e < 16; ++e) {
            int li = threadIdx.x + e * 256;
            int hi = li >> 6, lo = li & 63;
            sU[hi * 65 + lo] = U[(size_t)o0 * 64 + li];
            sT[li]           = T2[hi * 2048 + i0 + lo];
        }
        __syncthreads();
        int o  = threadIdx.x >> 2;
        int ib = (threadIdx.x & 3) * 16;
        float acc[16] = {};
        for (int k = 0; k < 64; ++k) {
            float u = sU[o * 65 + k];
            #pragma unroll
            for (int j = 0; j < 16; ++j) acc[j] += u * sT[k * 64 + ib + j];
        }
        size_t base = (size_t)(o0 + o) * 2048 + i0 + ib;
        #pragma unroll
        for (int j = 0; j < 16; ++j)
            Wb[base + j] = f2bf(W[base + j] + ALPHA_F * acc[j]);
    } else {
        int cb = blockIdx.x - 1024;   // 0..2047, each does 4 chunks of 2048 elems
        #pragma unroll
        for (int rep = 0; rep < 4; ++rep) {
            size_t idx = (((size_t)cb * 4 + rep) * 256 + threadIdx.x) * 8;
            f32x4 a = *reinterpret_cast<const f32x4*>(x + idx);
            f32x4 b = *reinterpret_cast<const f32x4*>(x + idx + 4);
            s16x8 o;
            o[0] = (short)f2bf(a[0]); o[1] = (short)f2bf(a[1]);
            o[2] = (short)f2bf(a[2]); o[3] = (short)f2bf(a[3]);
            o[4] = (short)f2bf(b[0]); o[5] = (short)f2bf(b[1]);
            o[6] = (short)f2bf(b[2]); o[7] = (short)f2bf(b[3]);
            *reinterpret_cast<s16x8*>(xb + idx) = o;
        }
    }
}

// ---------------- 256x256 8-phase bf16 MFMA GEMM ----------------
// (single barrier / phase; COMPILER-scheduled lgkm waits) — R10 best configuration.
// Phase = { ds_reads (a0, b0..b3, a1..a3 order); stage; [vmcnt]; s_barrier;
//           setprio(1); MFMA (compiler emits fine-grained lgkmcnt(N)); setprio(0) }.

#define AHALF_E (128 * K_DIM)   // elements per 128-row half panel

__device__ __forceinline__ void stage_slot(const unsigned short* g0, const unsigned short* g1,
                                           char* smp, int ldsbase, int wave) {
    gload_lds16(g0, smp + ldsbase + wave * 1024);
    gload_lds16(g1, smp + ldsbase + 8192 + wave * 1024);
}

// fragment reads, ordered so the FIRST MFMA's operands complete earliest (in-order lgkm)
template <int B_, int P_>
__device__ __forceinline__ void read_frags(const char* sm, s16x8 (&af)[4],
                                           s16x8 (&bfr4)[4][2],
                                           int wr8, int wc4, int laneoff) {
    constexpr int ks = P_ & 1, mh = P_ >> 1;
    af[0] = *(const s16x8*)(sm + B_ * 32768 + ((wr8 + mh * 4 + 0) * 2 + ks) * 1024 + laneoff);
    if (P_ < 2) {
        #pragma unroll
        for (int ni = 0; ni < 4; ++ni)
            bfr4[ni][ks] = *(const s16x8*)(sm + 65536 + B_ * 32768 +
                              ((wc4 + ni) * 2 + ks) * 1024 + laneoff);
    }
    #pragma unroll
    for (int mi = 1; mi < 4; ++mi)
        af[mi] = *(const s16x8*)(sm + B_ * 32768 +
                    ((wr8 + mh * 4 + mi) * 2 + ks) * 1024 + laneoff);
}

template <int P_>
__device__ __forceinline__ void mfma_p(f32x4 (&acc)[8][4], s16x8 (&af)[4], s16x8 (&bfr4)[4][2]) {
    constexpr int ks = P_ & 1, mh = P_ >> 1;
    #pragma unroll
    for (int mi = 0; mi < 4; ++mi)
        #pragma unroll
        for (int ni = 0; ni < 4; ++ni)
            acc[mh * 4 + mi][ni] = __builtin_amdgcn_mfma_f32_16x16x32_bf16(
                af[mi], bfr4[ni][ks], acc[mh * 4 + mi][ni], 0, 0, 0);
}

#define VMWAIT2 do { asm volatile("s_waitcnt vmcnt(2)" ::: "memory"); \
                     __builtin_amdgcn_sched_barrier(0); } while (0)
#define VMWAIT4 do { asm volatile("s_waitcnt vmcnt(4)" ::: "memory"); \
                     __builtin_amdgcn_sched_barrier(0); } while (0)

// single-barrier phase, compiler-scheduled LDS waits
#define DO_PHASE(B_, P_, STAGE_STMT, WAIT_STMT)                         \
  { s16x8 af[4];                                                        \
    read_frags<B_, P_>(sm, af, bfr4, wr8, wc4, laneoff);                \
    STAGE_STMT;                                                         \
    WAIT_STMT;                                                          \
    __builtin_amdgcn_s_barrier();                                       \
    __builtin_amdgcn_s_setprio(1);                                      \
    mfma_p<P_>(acc, af, bfr4);                                          \
    __builtin_amdgcn_s_setprio(0); }

#define STAGE_A(half, buf, kel) \
    stage_slot(Ag + (half) * AHALF_E + (kel) + soff0, Ag + (half) * AHALF_E + (kel) + soff1, \
               sm, (buf) * 32768 + (half) * 16384, wave)
#define STAGE_B(half, buf, kel) \
    stage_slot(Bg + (half) * AHALF_E + (kel) + soff0, Bg + (half) * AHALF_E + (kel) + soff1, \
               sm, 65536 + (buf) * 32768 + (half) * 16384, wave)

__global__ __launch_bounds__(512, 2)
void gemm8_kernel(const unsigned short* __restrict__ A,
                  const unsigned short* __restrict__ Bm,
                  const float* __restrict__ bias,
                  float* __restrict__ C) {
    extern __shared__ char sm[];

    const int tid  = threadIdx.x;
    const int wave = tid >> 6;
    const int lane = tid & 63;
    const int wr8  = (wave >> 2) * 8;   // A subtile row base (16-row units)
    const int wc4  = (wave & 3) * 4;    // B subtile row base

    // XCD-bijective swizzle: 256 blocks, 256 % 8 == 0
    const int bid = blockIdx.x;
    const int swz = (bid & 7) * 32 + (bid >> 3);
    const int rowM0 = (swz >> 3) * 256;   // 32 M-tiles
    const int rowN0 = (swz & 7) * 256;    // 8 N-tiles

    const unsigned short* Ag = A  + (size_t)rowM0 * K_DIM;
    const unsigned short* Bg = Bm + (size_t)rowN0 * K_DIM;

    // staging source: linear LDS dest byte D -> global element (slot-swizzled layout)
    int soff0, soff1;
    {
        #pragma unroll
        for (int ld = 0; ld < 2; ++ld) {
            int D   = ld * 8192 + tid * 16;
            int st  = D >> 10;           // subtile unit in half-panel
            int s   = (D >> 4) & 63;     // slot within subtile
            int row = s >> 2;
            int kq  = (s & 3) ^ ((s >> 3) & 3);
            int e = ((st >> 1) * 16 + row) * K_DIM + (st & 1) * 32 + kq * 8;
            if (ld == 0) soff0 = e; else soff1 = e;
        }
    }

    // fragment ds_read lane offset (slot-swizzled)
    const int laneoff = ((lane & 15) * 4 + ((lane >> 4) ^ (((lane & 15) >> 1) & 3))) * 16;

    f32x4 acc[8][4] = {};
    s16x8 bfr4[4][2];

    // ---- prologue: tile0 -> buf0 (A0,A1,B0,B1), tile1 B -> buf1 ----
    STAGE_A(0, 0, 0);
    STAGE_A(1, 0, 0);
    STAGE_B(0, 0, 0);
    STAGE_B(1, 0, 0);
    STAGE_B(0, 1, 64);
    STAGE_B(1, 1, 64);
    VMWAIT4;
    __builtin_amdgcn_s_barrier();

    // ---- main loop: 16 iterations x 2 K-tiles ----
    // Stage ring (tile t=2i in buf0, t+1 in buf1):
    //  ph1: A-buf1(t+1) h0   ph2: A-buf1 h1    ph3: -        ph4: B-buf0(t+2) h0 [vmcnt(2)]
    //  ph5: B-buf0 h1        ph6: A-buf0(t+2) h0  ph7: A-buf0 h1
    //  ph8: B-buf1(t+3) h0+h1 [vmcnt(4)]
    for (int i = 0; i < 16; ++i) {
        const int kA12 = (2 * i + 1) * 64;          // tile 2i+1 (always valid)
        const int kN2  = ((2 * i + 2) & 31) * 64;   // tile 2i+2 (clamped tail)
        const int kN3  = ((2 * i + 3) & 31) * 64;   // tile 2i+3 (clamped tail)

        DO_PHASE(0, 0, STAGE_A(0, 1, kA12), ((void)0));
        DO_PHASE(0, 1, STAGE_A(1, 1, kA12), ((void)0));
        DO_PHASE(0, 2, ((void)0),           ((void)0));
        DO_PHASE(0, 3, STAGE_B(0, 0, kN2),  VMWAIT2);
        DO_PHASE(1, 0, STAGE_B(1, 0, kN2),  ((void)0));
        DO_PHASE(1, 1, STAGE_A(0, 0, kN2),  ((void)0));
        DO_PHASE(1, 2, STAGE_A(1, 0, kN2),  ((void)0));
        DO_PHASE(1, 3, (STAGE_B(0, 1, kN3), STAGE_B(1, 1, kN3)), VMWAIT4);
    }

    // ---- epilogue: D row=(lane>>4)*4+r, col=lane&15 per 16x16 fragment ----
    const int col0  = rowN0 + (wc4 >> 2) * 64 + (lane & 15);
    const int row0w = rowM0 + (wr8 >> 3) * 128 + (lane >> 4) * 4;
    float bv[4];
    #pragma unroll
    for (int ni = 0; ni < 4; ++ni) bv[ni] = bias[col0 + ni * 16];
    #pragma unroll
    for (int mi = 0; mi < 8; ++mi)
        #pragma unroll
        for (int ni = 0; ni < 4; ++ni)
            #pragma unroll
            for (int r = 0; r < 4; ++r)
                C[(size_t)(row0w + mi * 16 + r) * N_DIM + col0 + ni * 16] =
                    acc[mi][ni][r] + bv[ni];
}

// ---------------- fp32 fallback (only if ws too small for bf16 path) ----------------

__global__ __launch_bounds__(256) void xt_kernel(const float* __restrict__ x,
                                                 const float* __restrict__ T2,
                                                 float* __restrict__ xt) {
    int idx = blockIdx.x * 256 + threadIdx.x;
    int m = idx >> 6, r = idx & 63;
    float acc = 0.f;
    for (int i = 0; i < K_DIM; ++i) acc += x[(size_t)m * K_DIM + i] * T2[r * K_DIM + i];
    xt[idx] = acc;
}

__global__ __launch_bounds__(256) void fgemm_kernel(const float* __restrict__ A,
                                                    const float* __restrict__ W,
                                                    const float* __restrict__ xt,
                                                    const float* __restrict__ U,
                                                    const float* __restrict__ bias,
                                                    float* __restrict__ C) {
    __shared__ float sA[64][17];
    __shared__ float sW[64][17];
    int bm = blockIdx.x >> 5;
    int bn = blockIdx.x & 31;
    int m0 = bm * 64, n0 = bn * 64;
    int tid = threadIdx.x;
    int tm = tid >> 4, tn = tid & 15;
    float acc[4][4] = {};
    for (int k0 = 0; k0 < K_DIM; k0 += 16) {
        int lr = tid >> 2;
        int lc = (tid & 3) * 4;
        #pragma unroll
        for (int j = 0; j < 4; ++j) {
            sA[lr][lc + j] = A[(size_t)(m0 + lr) * K_DIM + k0 + lc + j];
            sW[lr][lc + j] = W[(size_t)(n0 + lr) * K_DIM + k0 + lc + j];
        }
        __syncthreads();
        #pragma unroll
        for (int kk = 0; kk < 16; ++kk) {
            float av[4], wv[4];
            #pragma unroll
            for (int i = 0; i < 4; ++i) av[i] = sA[tm * 4 + i][kk];
            #pragma unroll
            for (int j = 0; j < 4; ++j) wv[j] = sW[tn * 4 + j][kk];
            #pragma unroll
            for (int i = 0; i < 4; ++i)
                #pragma unroll
                for (int j = 0; j < 4; ++j) acc[i][j] += av[i] * wv[j];
        }
        __syncthreads();
    }
    #pragma unroll
    for (int i = 0; i < 4; ++i) {
        int m = m0 + tm * 4 + i;
        #pragma unroll
        for (int j = 0; j < 4; ++j) {
            int n = n0 + tn * 4 + j;
            float l = 0.f;
            for (int r = 0; r < RANK; ++r) l += xt[(size_t)m * RANK + r] * U[(size_t)n * RANK + r];
            C[(size_t)m * N_DIM + n] = acc[i][j] + l + bias[n];
        }
    }
}

// ---------------- launch ----------------
extern "C" void kernel_launch(void* const* d_in, const int* in_sizes, int n_in,
                              void* d_out, int out_size, void* d_ws, size_t ws_size,
                              hipStream_t stream) {
    const float* x      = (const float*)d_in[0];
    const float* weight = (const float*)d_in[1];
    const float* bias   = (const float*)d_in[2];
    const float* U      = (const float*)d_in[3];
    const float* sigma  = (const float*)d_in[4];
    const float* Rm     = (const float*)d_in[5];
    const float* Vt     = (const float*)d_in[6];
    float* out = (float*)d_out;
    char* ws = (char*)d_ws;

    const size_t XB_BYTES = (size_t)M_DIM * K_DIM * 2;   // 32 MB
    const size_t WB_BYTES = (size_t)N_DIM * K_DIM * 2;   // 8 MB
    const size_t T2_BYTES = (size_t)RANK * K_DIM * 4;    // 512 KB
    const size_t MAIN_NEED = XB_BYTES + WB_BYTES + T2_BYTES;

    if (ws_size >= MAIN_NEED) {
        unsigned short* xb = (unsigned short*)ws;
        unsigned short* wb = (unsigned short*)(ws + XB_BYTES);
        float* T2 = (float*)(ws + XB_BYTES + WB_BYTES);

        hipFuncSetAttribute((const void*)gemm8_kernel,
                            hipFuncAttributeMaxDynamicSharedMemorySize, 131072);

        t2sr_kernel<<<512, 256, 0, stream>>>(sigma, Rm, Vt, T2);
        weffcast_kernel<<<3072, 256, 0, stream>>>(weight, U, T2, wb, x, xb);
        gemm8_kernel<<<(M_DIM / 256) * (N_DIM / 256), 512, 131072, stream>>>(xb, wb, bias, out);
    } else {
        float* T2 = (float*)ws;
        float* xt = (float*)(ws + T2_BYTES);
        t2sr_kernel<<<512, 256, 0, stream>>>(sigma, Rm, Vt, T2);
        xt_kernel<<<(M_DIM * RANK) / 256, 256, 0, stream>>>(x, T2, xt);
        fgemm_kernel<<<(M_DIM / 64) * (N_DIM / 64), 256, 0, stream>>>(x, weight, xt, U, bias, out);
    }
}